// Round 2
// baseline (824.703 us; speedup 1.0000x reference)
//
#include <hip/hip_runtime.h>

typedef __attribute__((ext_vector_type(4))) float f32x4;
typedef __attribute__((ext_vector_type(8))) short s16x8;

#define RS 68  // LDS row stride (floats): 64 + 4 pad to break b128 bank conflicts

__device__ __forceinline__ unsigned short f2bf(float f) {
  unsigned int u = __builtin_bit_cast(unsigned int, f);
  u = (u + 0x7fffu + ((u >> 16) & 1u)) >> 16;  // RNE
  return (unsigned short)u;
}

__device__ __forceinline__ f32x4 mfma16(s16x8 a, s16x8 b, f32x4 c) {
  return __builtin_amdgcn_mfma_f32_16x16x32_bf16(a, b, c, 0, 0, 0);
}

__device__ __forceinline__ s16x8 ldfrag(const unsigned short* __restrict__ frags, int idx, int l) {
  return *reinterpret_cast<const s16x8*>(frags + idx * 512 + l * 8);
}

// ---------------- prep 1: Wcomb = Wv*Wk composition (fp32 exact), bv2 ----------------
__global__ void prep_comb(const float* __restrict__ Wk, const float* __restrict__ Wv,
                          const float* __restrict__ bk, const float* __restrict__ bv,
                          float* __restrict__ wcomb, float* __restrict__ bv2) {
  const int i = blockIdx.x;   // 0..63 (k-input index)
  const int o = threadIdx.x;  // 0..63 (v-output index)
  float s = 0.f;
  for (int j = 0; j < 64; ++j) s += Wv[o * 64 + j] * Wk[j * 64 + i];
  wcomb[i * 64 + o] = s;
  if (i == 0) {
    float t = bv[o];
    for (int j = 0; j < 64; ++j) t += bk[j] * Wv[o * 64 + j];
    bv2[o] = t;
  }
}

// ---------------- prep 2: pack bf16 B-fragments in fragment order ----------------
// frag idx (within family) = kt*NT + nt ; elem (lane l, j): k = kt*32+(l>>4)*8+j, n = nt*16+(l&15)
// families: [0,16) Wkv(KT2,NT8)  [16,24) Wo(KT2,NT4)  [24,56) W1(KT2,NT16)  [56,88) W2(KT8,NT4)
__global__ void prep_pack(const float* __restrict__ Wk, const float* __restrict__ Wo,
                          const float* __restrict__ W1, const float* __restrict__ W2,
                          const float* __restrict__ wcomb, unsigned short* __restrict__ frags) {
  const int f = blockIdx.x;    // 0..87
  const int lx = threadIdx.x;  // 0..63
  int fi, NT, fam;
  if (f < 16)      { fam = 0; fi = f;      NT = 8;  }
  else if (f < 24) { fam = 1; fi = f - 16; NT = 4;  }
  else if (f < 56) { fam = 2; fi = f - 24; NT = 16; }
  else             { fam = 3; fi = f - 56; NT = 4;  }
  const int kt = fi / NT, nt = fi % NT;
#pragma unroll
  for (int j = 0; j < 8; ++j) {
    const int kk = kt * 32 + (lx >> 4) * 8 + j;
    const int nn = nt * 16 + (lx & 15);
    float v;
    if (fam == 0)      v = (nn < 64) ? Wk[nn * 64 + kk] : wcomb[kk * 64 + (nn - 64)];
    else if (fam == 1) v = Wo[nn * 64 + kk];
    else if (fam == 2) v = W1[nn * 64 + kk];
    else               v = W2[nn * 256 + kk];
    frags[f * 512 + lx * 8 + j] = f2bf(v);
  }
}

// ---------------- fused main: one wave per 16-token tile ----------------
__global__ void __launch_bounds__(64)
fused_main(const float* __restrict__ qin, const float* __restrict__ kin,
           const float* __restrict__ pin, const float* __restrict__ Wp,
           const float* __restrict__ bo, const float* __restrict__ b1,
           const float* __restrict__ b2, const float* __restrict__ g2,
           const float* __restrict__ be2,
           const unsigned short* __restrict__ frags,
           const float* __restrict__ bv2, float* __restrict__ outp) {
  __shared__ __align__(16) float r0[16 * RS];  // o2 (attn-out + residual)
  __shared__ __align__(16) float r1[16 * RS];  // o accum, then FFN1 quarter buffer
  const int l = threadIdx.x;
  const int m16 = l & 15;
  const int g = l >> 4;
  const int tok0 = (int)blockIdx.x * 16;
  const f32x4 zf = {0.f, 0.f, 0.f, 0.f};

  // resident Wkv fragments (k -> [kp | v], Wk and composed Wv*Wk)
  s16x8 wkv[2][8];
#pragma unroll
  for (int kt = 0; kt < 2; ++kt)
#pragma unroll
    for (int nt = 0; nt < 8; ++nt)
      wkv[kt][nt] = ldfrag(frags, kt * 8 + nt, l);

  // per-column constants (col = c*16 + m16)
  f32x4 wpr[4];
  float bvc[4];
#pragma unroll
  for (int c = 0; c < 4; ++c) {
    const int col = c * 16 + m16;
    wpr[c] = *reinterpret_cast<const f32x4*>(Wp + col * 4);
    bvc[c] = bv2[col];
  }

  // ---- P1: per-token neighbor attention ----
  // NOTE: qp, bk, bp are constant along the softmax axis (M) -> cancel exactly; omitted.
#pragma unroll 4
  for (int t = 0; t < 16; ++t) {
    const float* krow = kin + (size_t)(tok0 + t) * 1024 + m16 * 64 + g * 8;
    s16x8 ka[2];
#pragma unroll
    for (int kt = 0; kt < 2; ++kt) {
      const f32x4 a = *reinterpret_cast<const f32x4*>(krow + kt * 32);
      const f32x4 b = *reinterpret_cast<const f32x4*>(krow + kt * 32 + 4);
#pragma unroll
      for (int j = 0; j < 4; ++j) {
        ka[kt][j] = (short)f2bf(a[j]);
        ka[kt][j + 4] = (short)f2bf(b[j]);
      }
    }
    f32x4 p4[4];
#pragma unroll
    for (int r = 0; r < 4; ++r)
      p4[r] = *reinterpret_cast<const f32x4*>(pin + (size_t)(tok0 + t) * 64 + (g * 4 + r) * 4);

#pragma unroll
    for (int c = 0; c < 4; ++c) {
      f32x4 kp = mfma16(ka[0], wkv[0][c], zf);
      kp = mfma16(ka[1], wkv[1][c], kp);
      f32x4 vv = mfma16(ka[0], wkv[0][c + 4], zf);
      vv = mfma16(ka[1], wkv[1][c + 4], vv);
      // D layout: lane holds col = c*16+m16, rows m = g*4 + r
      float sv[4];
#pragma unroll
      for (int r = 0; r < 4; ++r)
        sv[r] = kp[r] + p4[r][0] * wpr[c][0] + p4[r][1] * wpr[c][1]
                      + p4[r][2] * wpr[c][2] + p4[r][3] * wpr[c][3];
      float mx = fmaxf(fmaxf(sv[0], sv[1]), fmaxf(sv[2], sv[3]));
      mx = fmaxf(mx, __shfl_xor(mx, 16));
      mx = fmaxf(mx, __shfl_xor(mx, 32));
      float ev[4], den = 0.f;
#pragma unroll
      for (int r = 0; r < 4; ++r) { ev[r] = __expf(sv[r] - mx); den += ev[r]; }
      den += __shfl_xor(den, 16);
      den += __shfl_xor(den, 32);
      float oc = 0.f;
#pragma unroll
      for (int r = 0; r < 4; ++r) oc += ev[r] * (vv[r] + bvc[c]);
      oc *= __builtin_amdgcn_rcpf(den);
      oc += __shfl_xor(oc, 16);
      oc += __shfl_xor(oc, 32);
      if (l < 16) r1[t * RS + c * 16 + l] = oc;
    }
  }
  __syncthreads();

  // ---- P2: o @ Wo^T + bo + q (residual) ----
  f32x4 o2[4];
  {
    s16x8 oa[2];
#pragma unroll
    for (int kt = 0; kt < 2; ++kt) {
      const f32x4 a = *reinterpret_cast<const f32x4*>(&r1[m16 * RS + kt * 32 + g * 8]);
      const f32x4 b = *reinterpret_cast<const f32x4*>(&r1[m16 * RS + kt * 32 + g * 8 + 4]);
#pragma unroll
      for (int j = 0; j < 4; ++j) {
        oa[kt][j] = (short)f2bf(a[j]);
        oa[kt][j + 4] = (short)f2bf(b[j]);
      }
    }
#pragma unroll
    for (int c = 0; c < 4; ++c) {
      f32x4 acc = zf;
      acc = mfma16(oa[0], ldfrag(frags, 16 + c, l), acc);
      acc = mfma16(oa[1], ldfrag(frags, 20 + c, l), acc);
      const float boc = bo[c * 16 + m16];
#pragma unroll
      for (int r = 0; r < 4; ++r)
        o2[c][r] = acc[r] + boc + qin[(size_t)(tok0 + g * 4 + r) * 64 + c * 16 + m16];
    }
  }
  __syncthreads();
#pragma unroll
  for (int c = 0; c < 4; ++c)
#pragma unroll
    for (int r = 0; r < 4; ++r)
      r0[(g * 4 + r) * RS + c * 16 + m16] = o2[c][r];
  __syncthreads();

  // ---- P3: LN2 (rows in A-layout, stats via shfl over the 4 lane-groups) ----
  s16x8 ha[2];
  {
    float x[16];
#pragma unroll
    for (int kt = 0; kt < 2; ++kt) {
      const f32x4 a = *reinterpret_cast<const f32x4*>(&r0[m16 * RS + kt * 32 + g * 8]);
      const f32x4 b = *reinterpret_cast<const f32x4*>(&r0[m16 * RS + kt * 32 + g * 8 + 4]);
#pragma unroll
      for (int j = 0; j < 4; ++j) { x[kt * 8 + j] = a[j]; x[kt * 8 + 4 + j] = b[j]; }
    }
    float s1 = 0.f, s2 = 0.f;
#pragma unroll
    for (int i = 0; i < 16; ++i) { s1 += x[i]; s2 += x[i] * x[i]; }
    s1 += __shfl_xor(s1, 16); s1 += __shfl_xor(s1, 32);
    s2 += __shfl_xor(s2, 16); s2 += __shfl_xor(s2, 32);
    const float mu = s1 * 0.015625f;
    const float var = s2 * 0.015625f - mu * mu;
    const float inv = __builtin_amdgcn_rsqf(var + 1e-5f);
#pragma unroll
    for (int kt = 0; kt < 2; ++kt)
#pragma unroll
      for (int j = 0; j < 8; ++j) {
        const int kk = kt * 32 + g * 8 + j;
        ha[kt][j] = (short)f2bf((x[kt * 8 + j] - mu) * inv * g2[kk] + be2[kk]);
      }
  }

  // ---- P4: FFN in 4 quarters of 64 F-columns (LDS transpose D->A between GEMMs) ----
  f32x4 f2acc[4];
#pragma unroll
  for (int c = 0; c < 4; ++c) f2acc[c] = zf;
  for (int qt = 0; qt < 4; ++qt) {
#pragma unroll
    for (int ct = 0; ct < 4; ++ct) {
      f32x4 acc = zf;
      acc = mfma16(ha[0], ldfrag(frags, 24 + qt * 4 + ct, l), acc);
      acc = mfma16(ha[1], ldfrag(frags, 40 + qt * 4 + ct, l), acc);
      const float b1c = b1[qt * 64 + ct * 16 + m16];
#pragma unroll
      for (int r = 0; r < 4; ++r)
        r1[(g * 4 + r) * RS + ct * 16 + m16] = fmaxf(acc[r] + b1c, 0.f);
    }
    __syncthreads();
    s16x8 h1a[2];
#pragma unroll
    for (int h = 0; h < 2; ++h) {
      const f32x4 a = *reinterpret_cast<const f32x4*>(&r1[m16 * RS + h * 32 + g * 8]);
      const f32x4 b = *reinterpret_cast<const f32x4*>(&r1[m16 * RS + h * 32 + g * 8 + 4]);
#pragma unroll
      for (int j = 0; j < 4; ++j) {
        h1a[h][j] = (short)f2bf(a[j]);
        h1a[h][j + 4] = (short)f2bf(b[j]);
      }
    }
#pragma unroll
    for (int c = 0; c < 4; ++c) {
      f2acc[c] = mfma16(h1a[0], ldfrag(frags, 56 + (qt * 2) * 4 + c, l), f2acc[c]);
      f2acc[c] = mfma16(h1a[1], ldfrag(frags, 56 + (qt * 2 + 1) * 4 + c, l), f2acc[c]);
    }
    __syncthreads();
  }

  // ---- P5: out = ffn2 + b2 + o2 ----
#pragma unroll
  for (int c = 0; c < 4; ++c) {
    const float b2c = b2[c * 16 + m16];
#pragma unroll
    for (int r = 0; r < 4; ++r)
      outp[(size_t)(tok0 + g * 4 + r) * 64 + c * 16 + m16] = f2acc[c][r] + b2c + o2[c][r];
  }
}

extern "C" void kernel_launch(void* const* d_in, const int* in_sizes, int n_in,
                              void* d_out, int out_size, void* d_ws, size_t ws_size,
                              hipStream_t stream) {
  (void)in_sizes; (void)n_in; (void)out_size; (void)ws_size;
  const float* q   = (const float*)d_in[0];
  const float* k   = (const float*)d_in[1];
  const float* pos = (const float*)d_in[2];
  // d_in[3]=Wq, d_in[4]=bq : provably dead (constant along softmax axis)
  const float* Wk  = (const float*)d_in[5];
  const float* bk  = (const float*)d_in[6];
  const float* Wv  = (const float*)d_in[7];
  const float* bv  = (const float*)d_in[8];
  const float* Wp  = (const float*)d_in[9];
  // d_in[10]=bp : dead (constant along softmax axis)
  const float* Wo  = (const float*)d_in[11];
  const float* bo  = (const float*)d_in[12];
  const float* W1  = (const float*)d_in[13];
  const float* b1  = (const float*)d_in[14];
  const float* W2  = (const float*)d_in[15];
  const float* b2  = (const float*)d_in[16];
  // d_in[17]=ln1_g, d_in[18]=ln1_b : dead (LN1 only feeds qp)
  const float* g2  = (const float*)d_in[19];
  const float* be2 = (const float*)d_in[20];

  unsigned short* frags = (unsigned short*)d_ws;              // 88 frags * 1024 B
  float* bv2   = (float*)((char*)d_ws + 90112);               // 64 f32
  float* wcomb = (float*)((char*)d_ws + 90368);               // 64x64 f32
  float* out = (float*)d_out;

  prep_comb<<<dim3(64), dim3(64), 0, stream>>>(Wk, Wv, bk, bv, wcomb, bv2);
  prep_pack<<<dim3(88), dim3(64), 0, stream>>>(Wk, Wo, W1, W2, wcomb, frags);
  fused_main<<<dim3(8192), dim3(64), 0, stream>>>(q, k, pos, Wp, bo, b1, b2, g2, be2,
                                                  (const unsigned short*)frags,
                                                  (const float*)bv2, out);
}